// Round 5
// baseline (255.359 us; speedup 1.0000x reference)
//
#include <hip/hip_runtime.h>
#include <utility>

#define NQ 6
#define DIM 64

namespace {

// ---- compile-time ring permutation (CNOT ladder), matching _ring_perm ----
constexpr int ring_entry(int r, int i) {
    int idx = i;
    for (int w = NQ - 1; w >= 0; --w) {
        int c = w;
        int t = (w + r) % NQ;
        int cbit = (idx >> (NQ - 1 - c)) & 1;
        idx ^= cbit << (NQ - 1 - t);
    }
    return idx;
}

// Logical->physical composed map after L rings (all rings are GF(2)-linear).
// Rings in order: R1 (after layer0), R2 (after layer1), R1 (after layer2).
constexpr int Mc(int L, int i) {
    if (L == 1) return ring_entry(1, i);
    if (L == 2) return ring_entry(1, ring_entry(2, i));
    if (L == 3) return ring_entry(1, ring_entry(2, ring_entry(1, i)));
    return i;
}

constexpr int Minv(int L, int p) {
    for (int i = 0; i < DIM; ++i) if (Mc(L, i) == p) return i;
    return -1;
}

} // namespace

// ---- 1-instr VALU lane swap (pairs 2r<->2r+1): DPP quad_perm [1,0,3,2] ----
__device__ __forceinline__ float swap1(float v) {
    return __int_as_float(__builtin_amdgcn_mov_dpp(__float_as_int(v), 0xB1, 0xF, 0xF, true));
}

// ===== gate application in the fixed physical frame via composed maps =====
// storage: my 32 regs hold physical slots (par, l); logical i = Minv(L, p).

template<int LY, int W, int d, int... Ls>
__device__ __forceinline__ void wire_inlane(float* sr, float* si,
        float A0r, float A0i, float B0r, float B0i,
        float A1r, float A1i, float B1r, float B1i,
        std::integer_sequence<int, Ls...>) {
    (([&] {
        if constexpr (Ls < (Ls ^ d)) {
            constexpr int la = Ls, lb = Ls ^ d;
            constexpr int ra = (Minv(LY, la) >> (5 - W)) & 1;
            constexpr int rb = (Minv(LY, lb) >> (5 - W)) & 1;
            const float cAar = ra ? A1r : A0r, cAai = ra ? A1i : A0i;
            const float cBar = ra ? B1r : B0r, cBai = ra ? B1i : B0i;
            const float cAbr = rb ? A1r : A0r, cAbi = rb ? A1i : A0i;
            const float cBbr = rb ? B1r : B0r, cBbi = rb ? B1i : B0i;
            const float mar = sr[la], mai = si[la];
            const float mbr = sr[lb], mbi = si[lb];
            sr[la] = cAar*mar - cAai*mai + cBar*mbr - cBai*mbi;
            si[la] = cAar*mai + cAai*mar + cBar*mbi + cBai*mbr;
            sr[lb] = cAbr*mbr - cAbi*mbi + cBbr*mar - cBbi*mai;
            si[lb] = cAbr*mbi + cAbi*mbr + cBbr*mai + cBbi*mar;
        }
    }()), ...);
}

template<int LY, int W, int... Ls>
__device__ __forceinline__ void wire_cross0(float* sr, float* si,
        float A0r, float A0i, float B0r, float B0i,
        float A1r, float A1i, float B1r, float B1i,
        std::integer_sequence<int, Ls...>) {
    (([&] {
        constexpr int r = (Minv(LY, Ls) >> (5 - W)) & 1;
        const float cAr = r ? A1r : A0r, cAi = r ? A1i : A0i;
        const float cBr = r ? B1r : B0r, cBi = r ? B1i : B0i;
        const float mr = sr[Ls], mi = si[Ls];
        const float tr = swap1(mr), ti = swap1(mi);   // reads precede writes (lockstep)
        sr[Ls] = cAr*mr - cAi*mi + cBr*tr - cBi*ti;
        si[Ls] = cAr*mi + cAi*mr + cBr*ti + cBi*tr;
    }()), ...);
}

template<int LY, int W, int d, int... Ls>
__device__ __forceinline__ void wire_crossd(float* sr, float* si,
        float A0r, float A0i, float B0r, float B0i,
        float A1r, float A1i, float B1r, float B1i,
        std::integer_sequence<int, Ls...>) {
    (([&] {
        if constexpr (Ls < (Ls ^ d)) {
            constexpr int la = Ls, lb = Ls ^ d;
            constexpr int ra = (Minv(LY, la) >> (5 - W)) & 1;
            constexpr int rb = (Minv(LY, lb) >> (5 - W)) & 1;
            const float cAar = ra ? A1r : A0r, cAai = ra ? A1i : A0i;
            const float cBar = ra ? B1r : B0r, cBai = ra ? B1i : B0i;
            const float cAbr = rb ? A1r : A0r, cAbi = rb ? A1i : A0i;
            const float cBbr = rb ? B1r : B0r, cBbi = rb ? B1i : B0i;
            const float mar = sr[la], mai = si[la];
            const float mbr = sr[lb], mbi = si[lb];
            const float tar = swap1(mbr), tai_ = swap1(mbi);  // partner old [lb]
            const float tbr = swap1(mar), tbi_ = swap1(mai);  // partner old [la]
            sr[la] = cAar*mar - cAai*mai + cBar*tar - cBai*tai_;
            si[la] = cAar*mai + cAai*mar + cBar*tai_ + cBai*tar;
            sr[lb] = cAbr*mbr - cAbi*mbi + cBbr*tbr - cBbi*tbi_;
            si[lb] = cAbr*mbi + cAbi*mbr + cBbr*tbi_ + cBbi*tbr;
        }
    }()), ...);
}

template<int LY, int W>
__device__ __forceinline__ void wire_apply(float* sr, float* si,
        const float* __restrict__ g, bool par) {
    constexpr int D = Mc(LY, 1 << (5 - W));     // physical pair offset (linear map)
    constexpr bool cross = (D >> 5) & 1;
    constexpr int d = D & 31;
    constexpr bool cpar = (Minv(LY, 32) >> (5 - W)) & 1;  // role flips with parity

    // role-hoisted coefficients: slot role = r0(l) ^ (par && cpar)
    float A0r, A0i, B0r, B0i, A1r, A1i, B1r, B1i;
    if constexpr (cpar) {
        A0r = par ? g[6] : g[0];  A0i = par ? g[7] : g[1];
        B0r = par ? g[4] : g[2];  B0i = par ? g[5] : g[3];
        A1r = par ? g[0] : g[6];  A1i = par ? g[1] : g[7];
        B1r = par ? g[2] : g[4];  B1i = par ? g[3] : g[5];
    } else {
        A0r = g[0]; A0i = g[1]; B0r = g[2]; B0i = g[3];
        A1r = g[6]; A1i = g[7]; B1r = g[4]; B1i = g[5];
    }
    if constexpr (!cross) {
        wire_inlane<LY, W, d>(sr, si, A0r, A0i, B0r, B0i, A1r, A1i, B1r, B1i,
                              std::make_integer_sequence<int, 32>{});
    } else if constexpr (d == 0) {
        wire_cross0<LY, W>(sr, si, A0r, A0i, B0r, B0i, A1r, A1i, B1r, B1i,
                           std::make_integer_sequence<int, 32>{});
    } else {
        wire_crossd<LY, W, d>(sr, si, A0r, A0i, B0r, B0i, A1r, A1i, B1r, B1i,
                              std::make_integer_sequence<int, 32>{});
    }
}

template<int LY>
__device__ __forceinline__ void layer_apply(float* sr, float* si,
        const float* __restrict__ g, bool par) {
    wire_apply<LY, 0>(sr, si, g,      par);
    wire_apply<LY, 1>(sr, si, g + 8,  par);
    wire_apply<LY, 2>(sr, si, g + 16, par);
    wire_apply<LY, 3>(sr, si, g + 24, par);
    wire_apply<LY, 4>(sr, si, g + 32, par);
    wire_apply<LY, 5>(sr, si, g + 40, par);
}

// ---- readout: fold full M3 into constexpr signs + one parity flip ----
template<int... Ls>
__device__ __forceinline__ void readout_impl(const float* sr, const float* si, float* q,
                                             std::integer_sequence<int, Ls...>) {
    (([&] {
        constexpr int iv = Minv(3, Ls);
        const float pb = sr[Ls]*sr[Ls] + si[Ls]*si[Ls];
        q[0] += ((iv >> 5) & 1) ? -pb : pb;
        q[1] += ((iv >> 4) & 1) ? -pb : pb;
        q[2] += ((iv >> 3) & 1) ? -pb : pb;
        q[3] += ((iv >> 2) & 1) ? -pb : pb;
        q[4] += ((iv >> 1) & 1) ? -pb : pb;
        q[5] += ( iv       & 1) ? -pb : pb;
    }()), ...);
}

// ---- per-thread gate computation (fallback path only) ----
__device__ __forceinline__ void compute_gates6(const float* __restrict__ th, float* g) {
#pragma unroll
    for (int w = 0; w < NQ; ++w) {
        const float phi = th[w*3+0], theta = th[w*3+1], omega = th[w*3+2];
        float s, c, sa, ca, sb, cb;
        __sincosf(0.5f * theta, &s, &c);
        __sincosf(0.5f * (phi + omega), &sa, &ca);
        __sincosf(0.5f * (phi - omega), &sb, &cb);
        g[w*8+0] =  ca * c;  g[w*8+1] = -sa * c;
        g[w*8+2] = -cb * s;  g[w*8+3] = -sb * s;
        g[w*8+4] =  cb * s;  g[w*8+5] = -sb * s;
        g[w*8+6] =  ca * c;  g[w*8+7] =  sa * c;
    }
}

// ---- setup: gates (18x8) + Gt[j][m] = ln_g[j]*W2[m][j] (64x6) + C1/C2 ----
// ws floats: [0,144) gates, [144,528) Gt (j*6+m), [528,534) C1, [534,540) C2+b2
__global__ void setup_kernel(const float* __restrict__ th_s, const float* __restrict__ th_t,
                             const float* __restrict__ ln_g, const float* __restrict__ ln_b,
                             const float* __restrict__ W2, const float* __restrict__ b2,
                             float* __restrict__ ws) {
    const int t = threadIdx.x;
    if (t < 18) {
        const int l = t / 6, w = t % 6;
        const float* th = (l < 2) ? (th_s + (l * 6 + w) * 3) : (th_t + w * 3);
        const float phi = th[0], theta = th[1], omega = th[2];
        float s, c, sa, ca, sb, cb;
        sincosf(0.5f * theta, &s, &c);
        sincosf(0.5f * (phi + omega), &sa, &ca);
        sincosf(0.5f * (phi - omega), &sb, &cb);
        float* g = ws + t * 8;
        g[0] =  ca * c;  g[1] = -sa * c;
        g[2] = -cb * s;  g[3] = -sb * s;
        g[4] =  cb * s;  g[5] = -sb * s;
        g[6] =  ca * c;  g[7] =  sa * c;
    }
    if (t < 384) {
        const int j = t / 6, m = t % 6;
        ws[144 + t] = ln_g[j] * W2[m * 64 + j];
    }
    if (t < 6) {
        float c1 = 0.f, c2 = 0.f;
        for (int j = 0; j < 64; ++j) {
            c1 += ln_g[j] * W2[t * 64 + j];
            c2 += ln_b[j] * W2[t * 64 + j];
        }
        ws[528 + t] = c1;
        ws[534 + t] = c2 + b2[t];
    }
}

template<bool USE_WS>
__global__ __launch_bounds__(256, 4)   // cap 128 VGPR, 4 waves/EU
void qmaml_kernel(
    const float* __restrict__ x,  const float* __restrict__ W1, const float* __restrict__ b1,
    const float* __restrict__ ln_g, const float* __restrict__ ln_b,
    const float* __restrict__ W2, const float* __restrict__ b2,
    const float* __restrict__ th_s, const float* __restrict__ th_t,
    const float* __restrict__ Wc, const float* __restrict__ bc,
    const float* __restrict__ ws, float* __restrict__ out, int nrows) {

    const int t   = blockIdx.x * 256 + threadIdx.x;
    const int row = t >> 1;
    const bool par = t & 1;            // = logical wire-0 bit of my half-state
    if (row >= nrows) return;

    // ---- load x row (both lanes of a pair load the same row) ----
    float4 xv[16];
    const float4* xp = (const float4*)(x + (long)row * 64);
#pragma unroll
    for (int k = 0; k < 16; ++k) xv[k] = xp[k];

    // ---- fused matvec + relu + LN-stats + folded (g*W2) projection ----
    // j-SPLIT across the lane pair: even lane j in [0,32), odd lane [32,64).
    float A[6]  = {0.f, 0.f, 0.f, 0.f, 0.f, 0.f};
    float C1[6] = {0.f, 0.f, 0.f, 0.f, 0.f, 0.f};
    float C2[6] = {0.f, 0.f, 0.f, 0.f, 0.f, 0.f};
    float s = 0.f, s2 = 0.f;

    const int jbase = par ? 32 : 0;
    const float4* __restrict__ wbase = (const float4*)(W1 + jbase * 64);
    const float*  __restrict__ bbase = b1 + jbase;

    for (int jj = 0; jj < 32; ++jj) {
        const float4* wr = wbase + jj * 16;
        float acc = bbase[jj];
#pragma unroll
        for (int k = 0; k < 16; ++k) {
            const float4 w4 = wr[k];
            acc = fmaf(w4.x, xv[k].x, acc);
            acc = fmaf(w4.y, xv[k].y, acc);
            acc = fmaf(w4.z, xv[k].z, acc);
            acc = fmaf(w4.w, xv[k].w, acc);
        }
        acc = fmaxf(acc, 0.f);
        s += acc; s2 += acc * acc;
        if constexpr (USE_WS) {
            const float* Gt = ws + 144 + (jbase + jj) * 6;
#pragma unroll
            for (int m = 0; m < 6; ++m) A[m] = fmaf(acc, Gt[m], A[m]);
        } else {
            const int j = jbase + jj;
            const float gj = ln_g[j], bj = ln_b[j];
#pragma unroll
            for (int m = 0; m < 6; ++m) {
                const float w2 = W2[m * 64 + j];
                const float gw = gj * w2;
                A[m]  = fmaf(acc, gw, A[m]);
                C1[m] += gw;
                C2[m] = fmaf(bj, w2, C2[m]);
            }
        }
    }

    // ---- combine partial sums across the lane pair (both lanes get full) ----
    s  = s  + swap1(s);
    s2 = s2 + swap1(s2);
#pragma unroll
    for (int m = 0; m < 6; ++m) A[m] = A[m] + swap1(A[m]);
    if constexpr (!USE_WS) {
#pragma unroll
        for (int m = 0; m < 6; ++m) {
            C1[m] = C1[m] + swap1(C1[m]);
            C2[m] = C2[m] + swap1(C2[m]);
        }
    }

    const float mu  = s  * (1.f / 64.f);
    const float var = s2 * (1.f / 64.f) - mu * mu;
    const float inv = rsqrtf(var + 1e-5f);

    // ---- z = tanh(...), per-wire (cos, sin) ----
    float vc[6], vsn[6];
#pragma unroll
    for (int m = 0; m < 6; ++m) {
        float c1v, c2v;
        if constexpr (USE_WS) { c1v = ws[528 + m]; c2v = ws[534 + m]; }
        else                  { c1v = C1[m];       c2v = C2[m] + b2[m]; }
        const float zp = inv * (A[m] - mu * c1v) + c2v;
        const float e  = __expf(2.f * zp);
        const float z  = 1.f - 2.f / (e + 1.f);
        const float half = 1.57079632679f * z;
        vsn[m] = __sinf(half);
        vc[m]  = __cosf(half);
    }

    float gf[48];
    const float* g0;
    if constexpr (USE_WS) g0 = ws;
    else { compute_gates6(th_s, gf); g0 = gf; }

    // ---- layer-0 gates folded into per-wire product vectors ----
    float gar[6], gai[6], gbr[6], gbi[6];
#pragma unroll
    for (int w = 0; w < 6; ++w) {
        const float c = vc[w], sv = vsn[w];
        gar[w] = g0[w*8+0]*c + g0[w*8+2]*sv;
        gai[w] = g0[w*8+1]*c + g0[w*8+3]*sv;
        gbr[w] = g0[w*8+4]*c + g0[w*8+6]*sv;
        gbi[w] = g0[w*8+5]*c + g0[w*8+7]*sv;
    }

    // ---- build my half of the product state (32 amps; wire0 = parity) ----
    float c1r_[2], c1i_[2];
    {
        const float c0r = par ? gbr[0] : gar[0];
        const float c0i = par ? gbi[0] : gai[0];
#pragma unroll
        for (int k = 0; k < 2; ++k) {
            const float yr = k ? gbr[1] : gar[1], yi = k ? gbi[1] : gai[1];
            c1r_[k] = c0r * yr - c0i * yi;
            c1i_[k] = c0r * yi + c0i * yr;
        }
    }
    float c2r_[4], c2i_[4];
#pragma unroll
    for (int k = 0; k < 4; ++k) {
        const int h = k >> 1, b = k & 1;
        const float yr = b ? gbr[2] : gar[2], yi = b ? gbi[2] : gai[2];
        c2r_[k] = c1r_[h] * yr - c1i_[h] * yi;
        c2i_[k] = c1r_[h] * yi + c1i_[h] * yr;
    }
    float c3r[8], c3i[8];
#pragma unroll
    for (int k = 0; k < 8; ++k) {
        const int h = k >> 1, b = k & 1;
        const float yr = b ? gbr[3] : gar[3], yi = b ? gbi[3] : gai[3];
        c3r[k] = c2r_[h] * yr - c2i_[h] * yi;
        c3i[k] = c2r_[h] * yi + c2i_[h] * yr;
    }
    float c4r[16], c4i[16];
#pragma unroll
    for (int k = 0; k < 16; ++k) {
        const int h = k >> 1, b = k & 1;
        const float yr = b ? gbr[4] : gar[4], yi = b ? gbi[4] : gai[4];
        c4r[k] = c3r[h] * yr - c3i[h] * yi;
        c4i[k] = c3r[h] * yi + c3i[h] * yr;
    }
    float sr[32], si[32];
#pragma unroll
    for (int k = 0; k < 32; ++k) {
        const int h = k >> 1, b = k & 1;
        const float yr = b ? gbr[5] : gar[5], yi = b ? gbi[5] : gai[5];
        sr[k] = c4r[h] * yr - c4i[h] * yi;
        si[k] = c4r[h] * yi + c4i[h] * yr;
    }

    // ---- layers act through composed maps; NO physical permutations ----
    if constexpr (USE_WS) {
        layer_apply<1>(sr, si, ws + 48, par);
        layer_apply<2>(sr, si, ws + 96, par);
    } else {
        compute_gates6(th_s + 18, gf);
        layer_apply<1>(sr, si, gf, par);
        compute_gates6(th_t, gf);
        layer_apply<2>(sr, si, gf, par);
    }

    // ---- <Z_w> readout through M3 ----
    float q[6] = {0.f, 0.f, 0.f, 0.f, 0.f, 0.f};
    readout_impl(sr, si, q, std::make_integer_sequence<int, 32>{});

    const float pm = par ? -1.f : 1.f;
    constexpr int invC = Minv(3, 32);   // parity contribution to M3^-1
#pragma unroll
    for (int w = 0; w < 6; ++w) {
        float tq = q[w];
        if ((invC >> (5 - w)) & 1) tq *= pm;
        q[w] = tq + swap1(tq);
    }

    // ---- head: out = q @ Wc^T + bc (split store across the lane pair) ----
    float o[5];
#pragma unroll
    for (int n = 0; n < 5; ++n) {
        float v = bc[n];
#pragma unroll
        for (int w = 0; w < 6; ++w) v = fmaf(q[w], Wc[n * 6 + w], v);
        o[n] = v;
    }
    float* orow = out + (long)row * 5;
    if (!par) { orow[0] = o[0]; orow[1] = o[1]; orow[2] = o[2]; }
    else      { orow[3] = o[3]; orow[4] = o[4]; }
}

extern "C" void kernel_launch(void* const* d_in, const int* in_sizes, int n_in,
                              void* d_out, int out_size, void* d_ws, size_t ws_size,
                              hipStream_t stream) {
    const float* x   = (const float*)d_in[0];
    const float* W1  = (const float*)d_in[1];
    const float* b1  = (const float*)d_in[2];
    const float* lng = (const float*)d_in[3];
    const float* lnb = (const float*)d_in[4];
    const float* W2  = (const float*)d_in[5];
    const float* b2  = (const float*)d_in[6];
    const float* ths = (const float*)d_in[7];
    const float* tht = (const float*)d_in[8];
    const float* Wc  = (const float*)d_in[9];
    const float* bc  = (const float*)d_in[10];
    float* out = (float*)d_out;
    float* ws  = (float*)d_ws;

    const int nrows = in_sizes[0] / 64;              // 131072
    const int nthreads = nrows * 2;                  // 2 lanes per row
    const int grid = (nthreads + 255) / 256;

    if (ws_size >= 540 * sizeof(float)) {
        setup_kernel<<<1, 384, 0, stream>>>(ths, tht, lng, lnb, W2, b2, ws);
        qmaml_kernel<true><<<grid, 256, 0, stream>>>(x, W1, b1, lng, lnb, W2, b2,
                                                     ths, tht, Wc, bc, ws, out, nrows);
    } else {
        qmaml_kernel<false><<<grid, 256, 0, stream>>>(x, W1, b1, lng, lnb, W2, b2,
                                                      ths, tht, Wc, bc, nullptr, out, nrows);
    }
}

// Round 6
// 160.584 us; speedup vs baseline: 1.5902x; 1.5902x over previous
//
#include <hip/hip_runtime.h>
#include <utility>

#define NQ 6
#define DIM 64

namespace {

// ---- compile-time ring permutation (CNOT ladder), matching _ring_perm ----
constexpr int ring_entry(int r, int i) {
    int idx = i;
    for (int w = NQ - 1; w >= 0; --w) {
        int c = w;
        int t = (w + r) % NQ;
        int cbit = (idx >> (NQ - 1 - c)) & 1;
        idx ^= cbit << (NQ - 1 - t);
    }
    return idx;
}

// Logical->physical composed map after L rings (all rings are GF(2)-linear).
// Rings in order: R1 (after layer0), R2 (after layer1), R1 (after layer2).
constexpr int Mc(int L, int i) {
    if (L == 1) return ring_entry(1, i);
    if (L == 2) return ring_entry(1, ring_entry(2, i));
    if (L == 3) return ring_entry(1, ring_entry(2, ring_entry(1, i)));
    return i;
}

constexpr int Minv(int L, int p) {
    for (int i = 0; i < DIM; ++i) if (Mc(L, i) == p) return i;
    return -1;
}

} // namespace

typedef _Float16 h2_t __attribute__((ext_vector_type(2)));

// ---- 1-instr VALU lane swap (pairs 2r<->2r+1): DPP quad_perm [1,0,3,2] ----
__device__ __forceinline__ float swap1(float v) {
    return __int_as_float(__builtin_amdgcn_mov_dpp(__float_as_int(v), 0xB1, 0xF, 0xF, true));
}

// ===== gate application in the fixed physical frame via composed maps =====
// storage: my 32 regs hold physical slots (par, l); logical i = Minv(L, p).

template<int LY, int W, int d, int... Ls>
__device__ __forceinline__ void wire_inlane(float* sr, float* si,
        float A0r, float A0i, float B0r, float B0i,
        float A1r, float A1i, float B1r, float B1i,
        std::integer_sequence<int, Ls...>) {
    (([&] {
        if constexpr (Ls < (Ls ^ d)) {
            constexpr int la = Ls, lb = Ls ^ d;
            constexpr int ra = (Minv(LY, la) >> (5 - W)) & 1;
            constexpr int rb = (Minv(LY, lb) >> (5 - W)) & 1;
            const float cAar = ra ? A1r : A0r, cAai = ra ? A1i : A0i;
            const float cBar = ra ? B1r : B0r, cBai = ra ? B1i : B0i;
            const float cAbr = rb ? A1r : A0r, cAbi = rb ? A1i : A0i;
            const float cBbr = rb ? B1r : B0r, cBbi = rb ? B1i : B0i;
            const float mar = sr[la], mai = si[la];
            const float mbr = sr[lb], mbi = si[lb];
            sr[la] = cAar*mar - cAai*mai + cBar*mbr - cBai*mbi;
            si[la] = cAar*mai + cAai*mar + cBar*mbi + cBai*mbr;
            sr[lb] = cAbr*mbr - cAbi*mbi + cBbr*mar - cBbi*mai;
            si[lb] = cAbr*mbi + cAbi*mbr + cBbr*mai + cBbi*mar;
        }
    }()), ...);
}

template<int LY, int W, int... Ls>
__device__ __forceinline__ void wire_cross0(float* sr, float* si,
        float A0r, float A0i, float B0r, float B0i,
        float A1r, float A1i, float B1r, float B1i,
        std::integer_sequence<int, Ls...>) {
    (([&] {
        constexpr int r = (Minv(LY, Ls) >> (5 - W)) & 1;
        const float cAr = r ? A1r : A0r, cAi = r ? A1i : A0i;
        const float cBr = r ? B1r : B0r, cBi = r ? B1i : B0i;
        const float mr = sr[Ls], mi = si[Ls];
        const float tr = swap1(mr), ti = swap1(mi);   // reads precede writes (lockstep)
        sr[Ls] = cAr*mr - cAi*mi + cBr*tr - cBi*ti;
        si[Ls] = cAr*mi + cAi*mr + cBr*ti + cBi*tr;
    }()), ...);
}

template<int LY, int W, int d, int... Ls>
__device__ __forceinline__ void wire_crossd(float* sr, float* si,
        float A0r, float A0i, float B0r, float B0i,
        float A1r, float A1i, float B1r, float B1i,
        std::integer_sequence<int, Ls...>) {
    (([&] {
        if constexpr (Ls < (Ls ^ d)) {
            constexpr int la = Ls, lb = Ls ^ d;
            constexpr int ra = (Minv(LY, la) >> (5 - W)) & 1;
            constexpr int rb = (Minv(LY, lb) >> (5 - W)) & 1;
            const float cAar = ra ? A1r : A0r, cAai = ra ? A1i : A0i;
            const float cBar = ra ? B1r : B0r, cBai = ra ? B1i : B0i;
            const float cAbr = rb ? A1r : A0r, cAbi = rb ? A1i : A0i;
            const float cBbr = rb ? B1r : B0r, cBbi = rb ? B1i : B0i;
            const float mar = sr[la], mai = si[la];
            const float mbr = sr[lb], mbi = si[lb];
            const float tar = swap1(mbr), tai_ = swap1(mbi);  // partner old [lb]
            const float tbr = swap1(mar), tbi_ = swap1(mai);  // partner old [la]
            sr[la] = cAar*mar - cAai*mai + cBar*tar - cBai*tai_;
            si[la] = cAar*mai + cAai*mar + cBar*tai_ + cBai*tar;
            sr[lb] = cAbr*mbr - cAbi*mbi + cBbr*tbr - cBbi*tbi_;
            si[lb] = cAbr*mbi + cAbi*mbr + cBbr*tbi_ + cBbi*tbr;
        }
    }()), ...);
}

template<int LY, int W>
__device__ __forceinline__ void wire_apply(float* sr, float* si,
        const float* __restrict__ g, bool par) {
    constexpr int D = Mc(LY, 1 << (5 - W));     // physical pair offset (linear map)
    constexpr bool cross = (D >> 5) & 1;
    constexpr int d = D & 31;
    constexpr bool cpar = (Minv(LY, 32) >> (5 - W)) & 1;  // role flips with parity

    // role-hoisted coefficients: slot role = r0(l) ^ (par && cpar)
    float A0r, A0i, B0r, B0i, A1r, A1i, B1r, B1i;
    if constexpr (cpar) {
        A0r = par ? g[6] : g[0];  A0i = par ? g[7] : g[1];
        B0r = par ? g[4] : g[2];  B0i = par ? g[5] : g[3];
        A1r = par ? g[0] : g[6];  A1i = par ? g[1] : g[7];
        B1r = par ? g[2] : g[4];  B1i = par ? g[3] : g[5];
    } else {
        A0r = g[0]; A0i = g[1]; B0r = g[2]; B0i = g[3];
        A1r = g[6]; A1i = g[7]; B1r = g[4]; B1i = g[5];
    }
    if constexpr (!cross) {
        wire_inlane<LY, W, d>(sr, si, A0r, A0i, B0r, B0i, A1r, A1i, B1r, B1i,
                              std::make_integer_sequence<int, 32>{});
    } else if constexpr (d == 0) {
        wire_cross0<LY, W>(sr, si, A0r, A0i, B0r, B0i, A1r, A1i, B1r, B1i,
                           std::make_integer_sequence<int, 32>{});
    } else {
        wire_crossd<LY, W, d>(sr, si, A0r, A0i, B0r, B0i, A1r, A1i, B1r, B1i,
                              std::make_integer_sequence<int, 32>{});
    }
}

template<int LY>
__device__ __forceinline__ void layer_apply(float* sr, float* si,
        const float* __restrict__ g, bool par) {
    wire_apply<LY, 0>(sr, si, g,      par);
    wire_apply<LY, 1>(sr, si, g + 8,  par);
    wire_apply<LY, 2>(sr, si, g + 16, par);
    wire_apply<LY, 3>(sr, si, g + 24, par);
    wire_apply<LY, 4>(sr, si, g + 32, par);
    wire_apply<LY, 5>(sr, si, g + 40, par);
}

// ---- readout: fold full M3 into constexpr signs + one parity flip ----
template<int... Ls>
__device__ __forceinline__ void readout_impl(const float* sr, const float* si, float* q,
                                             std::integer_sequence<int, Ls...>) {
    (([&] {
        constexpr int iv = Minv(3, Ls);
        const float pb = sr[Ls]*sr[Ls] + si[Ls]*si[Ls];
        q[0] += ((iv >> 5) & 1) ? -pb : pb;
        q[1] += ((iv >> 4) & 1) ? -pb : pb;
        q[2] += ((iv >> 3) & 1) ? -pb : pb;
        q[3] += ((iv >> 2) & 1) ? -pb : pb;
        q[4] += ((iv >> 1) & 1) ? -pb : pb;
        q[5] += ( iv       & 1) ? -pb : pb;
    }()), ...);
}

// ---- per-thread gate computation (fallback path only) ----
__device__ __forceinline__ void compute_gates6(const float* __restrict__ th, float* g) {
#pragma unroll
    for (int w = 0; w < NQ; ++w) {
        const float phi = th[w*3+0], theta = th[w*3+1], omega = th[w*3+2];
        float s, c, sa, ca, sb, cb;
        __sincosf(0.5f * theta, &s, &c);
        __sincosf(0.5f * (phi + omega), &sa, &ca);
        __sincosf(0.5f * (phi - omega), &sb, &cb);
        g[w*8+0] =  ca * c;  g[w*8+1] = -sa * c;
        g[w*8+2] = -cb * s;  g[w*8+3] = -sb * s;
        g[w*8+4] =  cb * s;  g[w*8+5] = -sb * s;
        g[w*8+6] =  ca * c;  g[w*8+7] =  sa * c;
    }
}

// ---- setup: gates (18x8) + Gt[j][m] (64x6) + C1/C2 + W1 as packed f16 ----
// ws floats: [0,144) gates, [144,528) Gt (j*6+m), [528,534) C1, [534,540) C2+b2,
//            [540,2588) W1 as half2: slot i packs (W1[2i], W1[2i+1])
__global__ void setup_kernel(const float* __restrict__ th_s, const float* __restrict__ th_t,
                             const float* __restrict__ ln_g, const float* __restrict__ ln_b,
                             const float* __restrict__ W1, const float* __restrict__ W2,
                             const float* __restrict__ b2, float* __restrict__ ws) {
    const int t = threadIdx.x;
    if (t < 18) {
        const int l = t / 6, w = t % 6;
        const float* th = (l < 2) ? (th_s + (l * 6 + w) * 3) : (th_t + w * 3);
        const float phi = th[0], theta = th[1], omega = th[2];
        float s, c, sa, ca, sb, cb;
        sincosf(0.5f * theta, &s, &c);
        sincosf(0.5f * (phi + omega), &sa, &ca);
        sincosf(0.5f * (phi - omega), &sb, &cb);
        float* g = ws + t * 8;
        g[0] =  ca * c;  g[1] = -sa * c;
        g[2] = -cb * s;  g[3] = -sb * s;
        g[4] =  cb * s;  g[5] = -sb * s;
        g[6] =  ca * c;  g[7] =  sa * c;
    }
    if (t < 384) {
        const int j = t / 6, m = t % 6;
        ws[144 + t] = ln_g[j] * W2[m * 64 + j];
    }
    if (t < 6) {
        float c1 = 0.f, c2 = 0.f;
        for (int j = 0; j < 64; ++j) {
            c1 += ln_g[j] * W2[t * 64 + j];
            c2 += ln_b[j] * W2[t * 64 + j];
        }
        ws[528 + t] = c1;
        ws[534 + t] = c2 + b2[t];
    }
    // W1 -> f16 pairs (2048 slots)
    for (int i = t; i < 2048; i += 384) {
        union { h2_t h; float f; } u;
        u.h[0] = (_Float16)W1[2 * i];
        u.h[1] = (_Float16)W1[2 * i + 1];
        ws[540 + i] = u.f;
    }
}

template<bool USE_WS>
__global__ __launch_bounds__(256, 4)   // cap 128 VGPR, 4 waves/EU
void qmaml_kernel(
    const float* __restrict__ x,  const float* __restrict__ W1, const float* __restrict__ b1,
    const float* __restrict__ ln_g, const float* __restrict__ ln_b,
    const float* __restrict__ W2, const float* __restrict__ b2,
    const float* __restrict__ th_s, const float* __restrict__ th_t,
    const float* __restrict__ Wc, const float* __restrict__ bc,
    const float* __restrict__ ws, float* __restrict__ out, int nrows) {

    const int t   = blockIdx.x * 256 + threadIdx.x;
    const int row = t >> 1;
    const bool par = t & 1;            // = logical wire-0 bit of my half-state
    if (row >= nrows) return;

    // ---- load x row (both lanes of a pair load the same row) ----
    float4 xv[16];
    const float4* xp = (const float4*)(x + (long)row * 64);
#pragma unroll
    for (int k = 0; k < 16; ++k) xv[k] = xp[k];

    // ---- fused matvec + relu + LN-stats + folded (g*W2) projection ----
    // (redundant across the lane pair; keeps W1 loads wave-uniform s_loads)
    float A[6]  = {0.f, 0.f, 0.f, 0.f, 0.f, 0.f};
    float C1[6] = {0.f, 0.f, 0.f, 0.f, 0.f, 0.f};
    float C2[6] = {0.f, 0.f, 0.f, 0.f, 0.f, 0.f};
    float s = 0.f, s2 = 0.f;

    if constexpr (USE_WS) {
        // x row -> half2 (one-time, ~100 ops)
        h2_t xh[32];
#pragma unroll
        for (int k = 0; k < 16; ++k) {
            xh[2*k]   = h2_t{(_Float16)xv[k].x, (_Float16)xv[k].y};
            xh[2*k+1] = h2_t{(_Float16)xv[k].z, (_Float16)xv[k].w};
        }
        const float* __restrict__ wh = ws + 540;   // packed half2, wave-uniform
        for (int j = 0; j < 64; ++j) {
            const float* wr = wh + j * 32;
            float a0 = b1[j], a1 = 0.f;
#pragma unroll
            for (int k = 0; k < 32; k += 2) {
                a0 = __builtin_amdgcn_fdot2(__builtin_bit_cast(h2_t, wr[k]),   xh[k],   a0, false);
                a1 = __builtin_amdgcn_fdot2(__builtin_bit_cast(h2_t, wr[k+1]), xh[k+1], a1, false);
            }
            float acc = fmaxf(a0 + a1, 0.f);
            s += acc; s2 += acc * acc;
            const float* Gt = ws + 144 + j * 6;    // contiguous 6 coeffs, scalar load
#pragma unroll
            for (int m = 0; m < 6; ++m) A[m] = fmaf(acc, Gt[m], A[m]);
        }
    } else {
        for (int j = 0; j < 64; ++j) {
            const float4* wr = (const float4*)(W1 + j * 64);
            float acc = b1[j];
#pragma unroll
            for (int k = 0; k < 16; ++k) {
                const float4 w4 = wr[k];
                acc = fmaf(w4.x, xv[k].x, acc);
                acc = fmaf(w4.y, xv[k].y, acc);
                acc = fmaf(w4.z, xv[k].z, acc);
                acc = fmaf(w4.w, xv[k].w, acc);
            }
            acc = fmaxf(acc, 0.f);
            s += acc; s2 += acc * acc;
            const float gj = ln_g[j], bj = ln_b[j];
#pragma unroll
            for (int m = 0; m < 6; ++m) {
                const float w2 = W2[m * 64 + j];
                const float gw = gj * w2;
                A[m]  = fmaf(acc, gw, A[m]);
                C1[m] += gw;
                C2[m] = fmaf(bj, w2, C2[m]);
            }
        }
    }

    const float mu  = s  * (1.f / 64.f);
    const float var = s2 * (1.f / 64.f) - mu * mu;
    const float inv = rsqrtf(var + 1e-5f);

    // ---- z = tanh(...), per-wire (cos, sin) ----
    float vc[6], vsn[6];
#pragma unroll
    for (int m = 0; m < 6; ++m) {
        float c1v, c2v;
        if constexpr (USE_WS) { c1v = ws[528 + m]; c2v = ws[534 + m]; }
        else                  { c1v = C1[m];       c2v = C2[m] + b2[m]; }
        const float zp = inv * (A[m] - mu * c1v) + c2v;
        const float e  = __expf(2.f * zp);
        const float z  = 1.f - 2.f / (e + 1.f);
        const float half = 1.57079632679f * z;
        vsn[m] = __sinf(half);
        vc[m]  = __cosf(half);
    }

    float gf[48];
    const float* g0;
    if constexpr (USE_WS) g0 = ws;
    else { compute_gates6(th_s, gf); g0 = gf; }

    // ---- layer-0 gates folded into per-wire product vectors ----
    float gar[6], gai[6], gbr[6], gbi[6];
#pragma unroll
    for (int w = 0; w < 6; ++w) {
        const float c = vc[w], sv = vsn[w];
        gar[w] = g0[w*8+0]*c + g0[w*8+2]*sv;
        gai[w] = g0[w*8+1]*c + g0[w*8+3]*sv;
        gbr[w] = g0[w*8+4]*c + g0[w*8+6]*sv;
        gbi[w] = g0[w*8+5]*c + g0[w*8+7]*sv;
    }

    // ---- build my half of the product state (32 amps; wire0 = parity) ----
    float c1r_[2], c1i_[2];
    {
        const float c0r = par ? gbr[0] : gar[0];
        const float c0i = par ? gbi[0] : gai[0];
#pragma unroll
        for (int k = 0; k < 2; ++k) {
            const float yr = k ? gbr[1] : gar[1], yi = k ? gbi[1] : gai[1];
            c1r_[k] = c0r * yr - c0i * yi;
            c1i_[k] = c0r * yi + c0i * yr;
        }
    }
    float c2r_[4], c2i_[4];
#pragma unroll
    for (int k = 0; k < 4; ++k) {
        const int h = k >> 1, b = k & 1;
        const float yr = b ? gbr[2] : gar[2], yi = b ? gbi[2] : gai[2];
        c2r_[k] = c1r_[h] * yr - c1i_[h] * yi;
        c2i_[k] = c1r_[h] * yi + c1i_[h] * yr;
    }
    float c3r[8], c3i[8];
#pragma unroll
    for (int k = 0; k < 8; ++k) {
        const int h = k >> 1, b = k & 1;
        const float yr = b ? gbr[3] : gar[3], yi = b ? gbi[3] : gai[3];
        c3r[k] = c2r_[h] * yr - c2i_[h] * yi;
        c3i[k] = c2r_[h] * yi + c2i_[h] * yr;
    }
    float c4r[16], c4i[16];
#pragma unroll
    for (int k = 0; k < 16; ++k) {
        const int h = k >> 1, b = k & 1;
        const float yr = b ? gbr[4] : gar[4], yi = b ? gbi[4] : gai[4];
        c4r[k] = c3r[h] * yr - c3i[h] * yi;
        c4i[k] = c3r[h] * yi + c3i[h] * yr;
    }
    float sr[32], si[32];
#pragma unroll
    for (int k = 0; k < 32; ++k) {
        const int h = k >> 1, b = k & 1;
        const float yr = b ? gbr[5] : gar[5], yi = b ? gbi[5] : gai[5];
        sr[k] = c4r[h] * yr - c4i[h] * yi;
        si[k] = c4r[h] * yi + c4i[h] * yr;
    }

    // ---- layers act through composed maps; NO physical permutations ----
    if constexpr (USE_WS) {
        layer_apply<1>(sr, si, ws + 48, par);
        layer_apply<2>(sr, si, ws + 96, par);
    } else {
        compute_gates6(th_s + 18, gf);
        layer_apply<1>(sr, si, gf, par);
        compute_gates6(th_t, gf);
        layer_apply<2>(sr, si, gf, par);
    }

    // ---- <Z_w> readout through M3 ----
    float q[6] = {0.f, 0.f, 0.f, 0.f, 0.f, 0.f};
    readout_impl(sr, si, q, std::make_integer_sequence<int, 32>{});

    const float pm = par ? -1.f : 1.f;
    constexpr int invC = Minv(3, 32);   // parity contribution to M3^-1
#pragma unroll
    for (int w = 0; w < 6; ++w) {
        float tq = q[w];
        if ((invC >> (5 - w)) & 1) tq *= pm;
        q[w] = tq + swap1(tq);
    }

    // ---- head: out = q @ Wc^T + bc (split store across the lane pair) ----
    float o[5];
#pragma unroll
    for (int n = 0; n < 5; ++n) {
        float v = bc[n];
#pragma unroll
        for (int w = 0; w < 6; ++w) v = fmaf(q[w], Wc[n * 6 + w], v);
        o[n] = v;
    }
    float* orow = out + (long)row * 5;
    if (!par) { orow[0] = o[0]; orow[1] = o[1]; orow[2] = o[2]; }
    else      { orow[3] = o[3]; orow[4] = o[4]; }
}

extern "C" void kernel_launch(void* const* d_in, const int* in_sizes, int n_in,
                              void* d_out, int out_size, void* d_ws, size_t ws_size,
                              hipStream_t stream) {
    const float* x   = (const float*)d_in[0];
    const float* W1  = (const float*)d_in[1];
    const float* b1  = (const float*)d_in[2];
    const float* lng = (const float*)d_in[3];
    const float* lnb = (const float*)d_in[4];
    const float* W2  = (const float*)d_in[5];
    const float* b2  = (const float*)d_in[6];
    const float* ths = (const float*)d_in[7];
    const float* tht = (const float*)d_in[8];
    const float* Wc  = (const float*)d_in[9];
    const float* bc  = (const float*)d_in[10];
    float* out = (float*)d_out;
    float* ws  = (float*)d_ws;

    const int nrows = in_sizes[0] / 64;              // 131072
    const int nthreads = nrows * 2;                  // 2 lanes per row
    const int grid = (nthreads + 255) / 256;

    if (ws_size >= 2588 * sizeof(float)) {
        setup_kernel<<<1, 384, 0, stream>>>(ths, tht, lng, lnb, W1, W2, b2, ws);
        qmaml_kernel<true><<<grid, 256, 0, stream>>>(x, W1, b1, lng, lnb, W2, b2,
                                                     ths, tht, Wc, bc, ws, out, nrows);
    } else {
        qmaml_kernel<false><<<grid, 256, 0, stream>>>(x, W1, b1, lng, lnb, W2, b2,
                                                      ths, tht, Wc, bc, nullptr, out, nrows);
    }
}